// Round 2
// baseline (299.204 us; speedup 1.0000x reference)
//
#include <hip/hip_runtime.h>
#include <hip/hip_bf16.h>
#include <stdint.h>

#define N_BATCH 16384
#define D_IN    2048
#define E_OUT   512
#define K_CONV  1537   // D_IN - E_OUT + 1
#define EPS_N   1e-12f
#define NSPLIT  3      // split-K factor

typedef unsigned short u16;
typedef __bf16 bf16x8 __attribute__((ext_vector_type(8)));
typedef float  f32x4  __attribute__((ext_vector_type(4)));

__device__ __forceinline__ u16 f2bf(float f) {
    union { float f; unsigned int u; } a; a.f = f;
    unsigned int r = a.u + 0x7FFFu + ((a.u >> 16) & 1u);   // RNE
    return (u16)(r >> 16);
}

// ---------------- x fp32 -> bf16 (8 elems/thread) ----------------
__global__ __launch_bounds__(256) void cvt_x_kernel(const float* __restrict__ x,
                                                    u16* __restrict__ xb) {
    int t = blockIdx.x * 256 + threadIdx.x;
    const float4* x4 = (const float4*)x;
    float4 a = x4[2 * t];
    float4 b = x4[2 * t + 1];
    uint4 o;
    o.x = (unsigned)f2bf(a.x) | ((unsigned)f2bf(a.y) << 16);
    o.y = (unsigned)f2bf(a.z) | ((unsigned)f2bf(a.w) << 16);
    o.z = (unsigned)f2bf(b.x) | ((unsigned)f2bf(b.y) << 16);
    o.w = (unsigned)f2bf(b.z) | ((unsigned)f2bf(b.w) << 16);
    ((uint4*)xb)[t] = o;
}

// ---------------- densify banded W into bf16 (E_OUT x D_IN) ----------------
__global__ __launch_bounds__(256) void prep_w_kernel(const float* __restrict__ w,
                                                     u16* __restrict__ wb) {
    int idx = blockIdx.x * 256 + threadIdx.x;
    int e = idx >> 11;
    int d = idx & (D_IN - 1);
    int k = d - e;
    float v = (k >= 0 && k < K_CONV) ? w[e * K_CONV + k] : 0.0f;
    wb[idx] = f2bf(v);
}

// ---------------- split-K bf16 MFMA GEMM: P[z] = A * B^T (partial) ----------------
// A: (N_BATCH x D_IN) bf16; B: (E_OUT x D_IN) bf16; P: NSPLIT partial (N_BATCH x E_OUT) fp32
// Grid: 1536 blocks, decoded XCD-aware so one m-row's 12 blocks share an XCD's L2.
__global__ __launch_bounds__(256, 3) void gemm_split_kernel(const u16* __restrict__ A,
                                                            const u16* __restrict__ B,
                                                            float* __restrict__ P) {
    __shared__ __align__(16) u16 As[4][128][8];   // 8 KB, k-plane layout
    __shared__ __align__(16) u16 Bs[4][128][8];   // 8 KB

    const int tid  = threadIdx.x;
    const int lane = tid & 63;
    const int wave = tid >> 6;
    const int quad = lane >> 4;
    const int r16  = lane & 15;
    const int wm   = (wave >> 1) << 6;
    const int wn   = (wave & 1) << 6;

    // XCD-aware decode: xcd = L%8 (round-robin dispatch), 12 (4n x 3z) blocks of
    // one m-row adjacent in the per-XCD sequence -> A row-block stays in that L2.
    const int L = blockIdx.x;            // [0, 1536)
    const int xcd = L & 7;
    const int s   = L >> 3;              // [0, 192)
    const int nz  = s % 12;
    const int m_idx = xcd * 16 + s / 12; // [0, 128)
    const int n_idx = nz & 3;
    const int z     = nz >> 2;           // [0, 3)

    const int m0 = m_idx * 128;
    const int n0 = n_idx * 128;

    // band-limited K: full range for this n-block is [n0, n0+1664), 52 iters of 32
    const int it_start = (z * 52) / NSPLIT;        // 0, 17, 34
    const int it_end   = ((z + 1) * 52) / NSPLIT;  // 17, 34, 52
    const int n_iters  = it_end - it_start;
    const int k_begin  = n0 + it_start * 32;

    const int li0 = tid, li1 = tid + 256;
    const int ar0 = li0 & 127, ak0 = li0 >> 7;
    const int ar1 = li1 & 127, ak1 = li1 >> 7;

    const u16* ag0 = A + (size_t)(m0 + ar0) * D_IN + k_begin + ak0 * 8;
    const u16* ag1 = A + (size_t)(m0 + ar1) * D_IN + k_begin + ak1 * 8;
    const u16* bg0 = B + (size_t)(n0 + ar0) * D_IN + k_begin + ak0 * 8;
    const u16* bg1 = B + (size_t)(n0 + ar1) * D_IN + k_begin + ak1 * 8;

    u16* as0 = &As[0][0][0] + li0 * 8;
    u16* as1 = &As[0][0][0] + li1 * 8;
    u16* bs0 = &Bs[0][0][0] + li0 * 8;
    u16* bs1 = &Bs[0][0][0] + li1 * 8;

    f32x4 acc[4][4] = {};

    for (int it = 0; it < n_iters; ++it) {
        __builtin_amdgcn_global_load_lds((const __attribute__((address_space(1))) void*)ag0,
                                         (__attribute__((address_space(3))) void*)as0, 16, 0, 0);
        __builtin_amdgcn_global_load_lds((const __attribute__((address_space(1))) void*)ag1,
                                         (__attribute__((address_space(3))) void*)as1, 16, 0, 0);
        __builtin_amdgcn_global_load_lds((const __attribute__((address_space(1))) void*)bg0,
                                         (__attribute__((address_space(3))) void*)bs0, 16, 0, 0);
        __builtin_amdgcn_global_load_lds((const __attribute__((address_space(1))) void*)bg1,
                                         (__attribute__((address_space(3))) void*)bs1, 16, 0, 0);
        ag0 += 32; ag1 += 32; bg0 += 32; bg1 += 32;

        __syncthreads();

        bf16x8 af[4], bf[4];
#pragma unroll
        for (int t = 0; t < 4; ++t)
            af[t] = *(const bf16x8*)&As[quad][wm + t * 16 + r16][0];
#pragma unroll
        for (int t = 0; t < 4; ++t)
            bf[t] = *(const bf16x8*)&Bs[quad][wn + t * 16 + r16][0];

#pragma unroll
        for (int i = 0; i < 4; ++i)
#pragma unroll
            for (int j = 0; j < 4; ++j)
                acc[i][j] = __builtin_amdgcn_mfma_f32_16x16x32_bf16(af[i], bf[j], acc[i][j], 0, 0, 0);

        __syncthreads();
    }

    float* Pz = P + (size_t)z * N_BATCH * E_OUT;
#pragma unroll
    for (int j = 0; j < 4; ++j) {
        const int col = n0 + wn + j * 16 + r16;
#pragma unroll
        for (int i = 0; i < 4; ++i) {
            const int rowb = m0 + wm + i * 16 + quad * 4;
#pragma unroll
            for (int rg = 0; rg < 4; ++rg)
                Pz[(size_t)(rowb + rg) * E_OUT + col] = acc[i][j][rg];
        }
    }
}

// ---------------- fused reduce(3 partials) + bias + row L2 normalize ----------------
__global__ __launch_bounds__(256) void reduce_norm_kernel(const float* __restrict__ P,
                                                          const float* __restrict__ bias,
                                                          float* __restrict__ out) {
    const int wave = threadIdx.x >> 6;
    const int lane = threadIdx.x & 63;
    const size_t row = (size_t)blockIdx.x * 4 + wave;
    const float4* p0 = (const float4*)(P + row * E_OUT);
    const float4* p1 = (const float4*)(P + (size_t)N_BATCH * E_OUT + row * E_OUT);
    const float4* p2 = (const float4*)(P + (size_t)2 * N_BATCH * E_OUT + row * E_OUT);
    const float4* bv = (const float4*)bias;

    float4 r[2];
    float ss = 0.0f;
#pragma unroll
    for (int j = 0; j < 2; ++j) {
        const int idx = lane * 2 + j;
        float4 a = p0[idx], b = p1[idx], c = p2[idx], d = bv[idx];
        float4 v;
        v.x = a.x + b.x + c.x + d.x;
        v.y = a.y + b.y + c.y + d.y;
        v.z = a.z + b.z + c.z + d.z;
        v.w = a.w + b.w + c.w + d.w;
        ss += v.x * v.x + v.y * v.y + v.z * v.z + v.w * v.w;
        r[j] = v;
    }
#pragma unroll
    for (int off = 32; off > 0; off >>= 1) ss += __shfl_xor(ss, off, 64);
    const float inv = 1.0f / fmaxf(sqrtf(ss), EPS_N);
    float4* o = (float4*)(out + row * E_OUT);
#pragma unroll
    for (int j = 0; j < 2; ++j) {
        float4 v = r[j];
        v.x *= inv; v.y *= inv; v.z *= inv; v.w *= inv;
        o[lane * 2 + j] = v;
    }
}

// ---------------- fallback: fused naive fp32 (only if ws too small) ----------------
__global__ __launch_bounds__(256) void naive_kernel(const float* __restrict__ x,
                                                    const float* __restrict__ w,
                                                    const float* __restrict__ b,
                                                    float* __restrict__ out) {
    __shared__ float xs[D_IN];
    __shared__ float os[E_OUT];
    __shared__ float red[4];
    const int n = blockIdx.x;
    const float* xr = x + (size_t)n * D_IN;
    for (int i = threadIdx.x; i < D_IN; i += 256) xs[i] = xr[i];
    __syncthreads();
    for (int i = threadIdx.x; i < E_OUT; i += 256) {
        float s = b[i];
        const float* wr = w + (size_t)i * K_CONV;
        for (int k = 0; k < K_CONV; ++k) s += wr[k] * xs[i + k];
        os[i] = s;
    }
    __syncthreads();
    float ss = 0.0f;
    for (int i = threadIdx.x; i < E_OUT; i += 256) ss += os[i] * os[i];
#pragma unroll
    for (int off = 32; off > 0; off >>= 1) ss += __shfl_xor(ss, off, 64);
    if ((threadIdx.x & 63) == 0) red[threadIdx.x >> 6] = ss;
    __syncthreads();
    const float inv = 1.0f / fmaxf(sqrtf(red[0] + red[1] + red[2] + red[3]), EPS_N);
    float* orow = out + (size_t)n * E_OUT;
    for (int i = threadIdx.x; i < E_OUT; i += 256) orow[i] = os[i] * inv;
}

extern "C" void kernel_launch(void* const* d_in, const int* in_sizes, int n_in,
                              void* d_out, int out_size, void* d_ws, size_t ws_size,
                              hipStream_t stream) {
    const float* x = (const float*)d_in[0];
    const float* w = (const float*)d_in[1];
    const float* b = (const float*)d_in[2];
    float* out = (float*)d_out;

    const size_t xb_bytes = (size_t)N_BATCH * D_IN * sizeof(u16);             // 64 MiB
    const size_t wb_bytes = (size_t)E_OUT * D_IN * sizeof(u16);               //  2 MiB
    const size_t p_bytes  = (size_t)NSPLIT * N_BATCH * E_OUT * sizeof(float); // 96 MiB

    if (ws_size < xb_bytes + wb_bytes + p_bytes) {
        naive_kernel<<<N_BATCH, 256, 0, stream>>>(x, w, b, out);
        return;
    }

    u16*   xb = (u16*)d_ws;
    u16*   wb = (u16*)((char*)d_ws + xb_bytes);
    float* P  = (float*)((char*)d_ws + xb_bytes + wb_bytes);

    cvt_x_kernel<<<(N_BATCH * D_IN / 8) / 256, 256, 0, stream>>>(x, xb);
    prep_w_kernel<<<(E_OUT * D_IN) / 256, 256, 0, stream>>>(w, wb);

    gemm_split_kernel<<<128 * 4 * NSPLIT, 256, 0, stream>>>(xb, wb, P);

    reduce_norm_kernel<<<N_BATCH / 4, 256, 0, stream>>>(P, b, out);
}

// Round 3
// 284.209 us; speedup vs baseline: 1.0528x; 1.0528x over previous
//
#include <hip/hip_runtime.h>
#include <hip/hip_bf16.h>
#include <stdint.h>

#define N_BATCH 16384
#define D_IN    2048
#define E_OUT   512
#define K_CONV  1537   // D_IN - E_OUT + 1
#define EPS_N   1e-12f
#define NSPLIT  2      // split-K factor
#define BKD     64     // K-depth per barrier
#define N_ITERS 13     // 1664 / BKD / NSPLIT, uniform for every block

typedef unsigned short u16;
typedef __bf16 bf16x8 __attribute__((ext_vector_type(8)));
typedef float  f32x4  __attribute__((ext_vector_type(4)));

__device__ __forceinline__ u16 f2bf(float f) {
    union { float f; unsigned int u; } a; a.f = f;
    unsigned int r = a.u + 0x7FFFu + ((a.u >> 16) & 1u);   // RNE
    return (u16)(r >> 16);
}

// ---------------- x fp32 -> bf16 (8 elems/thread) ----------------
__global__ __launch_bounds__(256) void cvt_x_kernel(const float* __restrict__ x,
                                                    u16* __restrict__ xb) {
    int t = blockIdx.x * 256 + threadIdx.x;
    const float4* x4 = (const float4*)x;
    float4 a = x4[2 * t];
    float4 b = x4[2 * t + 1];
    uint4 o;
    o.x = (unsigned)f2bf(a.x) | ((unsigned)f2bf(a.y) << 16);
    o.y = (unsigned)f2bf(a.z) | ((unsigned)f2bf(a.w) << 16);
    o.z = (unsigned)f2bf(b.x) | ((unsigned)f2bf(b.y) << 16);
    o.w = (unsigned)f2bf(b.z) | ((unsigned)f2bf(b.w) << 16);
    ((uint4*)xb)[t] = o;
}

// ---------------- densify banded W into bf16 (E_OUT x D_IN) ----------------
__global__ __launch_bounds__(256) void prep_w_kernel(const float* __restrict__ w,
                                                     u16* __restrict__ wb) {
    int idx = blockIdx.x * 256 + threadIdx.x;
    int e = idx >> 11;
    int d = idx & (D_IN - 1);
    int k = d - e;
    float v = (k >= 0 && k < K_CONV) ? w[e * K_CONV + k] : 0.0f;
    wb[idx] = f2bf(v);
}

// ---------------- split-K bf16 MFMA GEMM: P[z] = A * B^T (partial) ----------------
// Grid: 1024 blocks, ALL co-resident at 4 blocks/CU. Decode puts the 8 blocks
// (4 n-tiles x 2 k-splits) of one m-row on ONE XCD (xcd = blockIdx % 8 round-robin),
// running in lockstep -> overlapping A k-slices hit that XCD's L2.
__global__ __launch_bounds__(256, 4) void gemm_split_kernel(const u16* __restrict__ A,
                                                            const u16* __restrict__ B,
                                                            float* __restrict__ P) {
    __shared__ __align__(16) u16 As[8][128][8];   // 16 KB, k-plane layout
    __shared__ __align__(16) u16 Bs[8][128][8];   // 16 KB

    const int tid  = threadIdx.x;
    const int lane = tid & 63;
    const int wave = tid >> 6;
    const int quad = lane >> 4;
    const int r16  = lane & 15;
    const int wm   = (wave >> 1) << 6;
    const int wn   = (wave & 1) << 6;

    const int L   = blockIdx.x;          // [0, 1024)
    const int x   = L & 7;               // XCD (assuming round-robin dispatch)
    const int t   = L >> 3;              // [0, 128)
    const int nz  = t & 7;               // 8 blocks of one m-row, same XCD, adjacent
    const int m_idx = (t >> 3) * 8 + x;  // [0, 128), m ≡ x (mod 8)
    const int n_idx = nz >> 1;           // [0, 4)
    const int z     = nz & 1;            // [0, 2)

    const int m0 = m_idx * 128;
    const int n0 = n_idx * 128;

    // band-limited K: this n-block needs k in [n0, n0+1664) = 26 x 64; split in 2
    const int k_begin = n0 + z * (N_ITERS * BKD);

    // staging: 16 KB per matrix per iter = 1024 16B-chunks, 256 threads -> 4 each
    const u16* ag[4];
    const u16* bg[4];
    u16* as_[4];
    u16* bs_[4];
#pragma unroll
    for (int c = 0; c < 4; ++c) {
        const int li  = tid + 256 * c;
        const int row = li & 127;
        const int kc  = li >> 7;         // [0, 8)
        ag[c] = A + (size_t)(m0 + row) * D_IN + k_begin + kc * 8;
        bg[c] = B + (size_t)(n0 + row) * D_IN + k_begin + kc * 8;
        as_[c] = &As[0][0][0] + li * 8;
        bs_[c] = &Bs[0][0][0] + li * 8;
    }

    f32x4 acc[4][4] = {};

    for (int it = 0; it < N_ITERS; ++it) {
#pragma unroll
        for (int c = 0; c < 4; ++c)
            __builtin_amdgcn_global_load_lds((const __attribute__((address_space(1))) void*)ag[c],
                                             (__attribute__((address_space(3))) void*)as_[c], 16, 0, 0);
#pragma unroll
        for (int c = 0; c < 4; ++c)
            __builtin_amdgcn_global_load_lds((const __attribute__((address_space(1))) void*)bg[c],
                                             (__attribute__((address_space(3))) void*)bs_[c], 16, 0, 0);
#pragma unroll
        for (int c = 0; c < 4; ++c) { ag[c] += BKD; bg[c] += BKD; }

        __syncthreads();

#pragma unroll
        for (int kk = 0; kk < 2; ++kk) {
            bf16x8 af[4], bf[4];
#pragma unroll
            for (int t4 = 0; t4 < 4; ++t4)
                af[t4] = *(const bf16x8*)&As[kk * 4 + quad][wm + t4 * 16 + r16][0];
#pragma unroll
            for (int t4 = 0; t4 < 4; ++t4)
                bf[t4] = *(const bf16x8*)&Bs[kk * 4 + quad][wn + t4 * 16 + r16][0];
#pragma unroll
            for (int i = 0; i < 4; ++i)
#pragma unroll
                for (int j = 0; j < 4; ++j)
                    acc[i][j] = __builtin_amdgcn_mfma_f32_16x16x32_bf16(af[i], bf[j], acc[i][j], 0, 0, 0);
        }

        __syncthreads();
    }

    float* Pz = P + (size_t)z * N_BATCH * E_OUT;
#pragma unroll
    for (int j = 0; j < 4; ++j) {
        const int col = n0 + wn + j * 16 + r16;
#pragma unroll
        for (int i = 0; i < 4; ++i) {
            const int rowb = m0 + wm + i * 16 + quad * 4;
#pragma unroll
            for (int rg = 0; rg < 4; ++rg)
                Pz[(size_t)(rowb + rg) * E_OUT + col] = acc[i][j][rg];
        }
    }
}

// ---------------- fused reduce(2 partials) + bias + row L2 normalize ----------------
__global__ __launch_bounds__(256) void reduce_norm_kernel(const float* __restrict__ P,
                                                          const float* __restrict__ bias,
                                                          float* __restrict__ out) {
    const int wave = threadIdx.x >> 6;
    const int lane = threadIdx.x & 63;
    const size_t row = (size_t)blockIdx.x * 4 + wave;
    const float4* p0 = (const float4*)(P + row * E_OUT);
    const float4* p1 = (const float4*)(P + (size_t)N_BATCH * E_OUT + row * E_OUT);
    const float4* bv = (const float4*)bias;

    float4 r[2];
    float ss = 0.0f;
#pragma unroll
    for (int j = 0; j < 2; ++j) {
        const int idx = lane * 2 + j;
        float4 a = p0[idx], b = p1[idx], d = bv[idx];
        float4 v;
        v.x = a.x + b.x + d.x;
        v.y = a.y + b.y + d.y;
        v.z = a.z + b.z + d.z;
        v.w = a.w + b.w + d.w;
        ss += v.x * v.x + v.y * v.y + v.z * v.z + v.w * v.w;
        r[j] = v;
    }
#pragma unroll
    for (int off = 32; off > 0; off >>= 1) ss += __shfl_xor(ss, off, 64);
    const float inv = 1.0f / fmaxf(sqrtf(ss), EPS_N);
    float4* o = (float4*)(out + row * E_OUT);
#pragma unroll
    for (int j = 0; j < 2; ++j) {
        float4 v = r[j];
        v.x *= inv; v.y *= inv; v.z *= inv; v.w *= inv;
        o[lane * 2 + j] = v;
    }
}

// ---------------- fallback: fused naive fp32 (only if ws too small) ----------------
__global__ __launch_bounds__(256) void naive_kernel(const float* __restrict__ x,
                                                    const float* __restrict__ w,
                                                    const float* __restrict__ b,
                                                    float* __restrict__ out) {
    __shared__ float xs[D_IN];
    __shared__ float os[E_OUT];
    __shared__ float red[4];
    const int n = blockIdx.x;
    const float* xr = x + (size_t)n * D_IN;
    for (int i = threadIdx.x; i < D_IN; i += 256) xs[i] = xr[i];
    __syncthreads();
    for (int i = threadIdx.x; i < E_OUT; i += 256) {
        float s = b[i];
        const float* wr = w + (size_t)i * K_CONV;
        for (int k = 0; k < K_CONV; ++k) s += wr[k] * xs[i + k];
        os[i] = s;
    }
    __syncthreads();
    float ss = 0.0f;
    for (int i = threadIdx.x; i < E_OUT; i += 256) ss += os[i] * os[i];
#pragma unroll
    for (int off = 32; off > 0; off >>= 1) ss += __shfl_xor(ss, off, 64);
    if ((threadIdx.x & 63) == 0) red[threadIdx.x >> 6] = ss;
    __syncthreads();
    const float inv = 1.0f / fmaxf(sqrtf(red[0] + red[1] + red[2] + red[3]), EPS_N);
    float* orow = out + (size_t)n * E_OUT;
    for (int i = threadIdx.x; i < E_OUT; i += 256) orow[i] = os[i] * inv;
}

extern "C" void kernel_launch(void* const* d_in, const int* in_sizes, int n_in,
                              void* d_out, int out_size, void* d_ws, size_t ws_size,
                              hipStream_t stream) {
    const float* x = (const float*)d_in[0];
    const float* w = (const float*)d_in[1];
    const float* b = (const float*)d_in[2];
    float* out = (float*)d_out;

    const size_t xb_bytes = (size_t)N_BATCH * D_IN * sizeof(u16);             // 64 MiB
    const size_t wb_bytes = (size_t)E_OUT * D_IN * sizeof(u16);               //  2 MiB
    const size_t p_bytes  = (size_t)NSPLIT * N_BATCH * E_OUT * sizeof(float); // 64 MiB

    if (ws_size < xb_bytes + wb_bytes + p_bytes) {
        naive_kernel<<<N_BATCH, 256, 0, stream>>>(x, w, b, out);
        return;
    }

    u16*   xb = (u16*)d_ws;
    u16*   wb = (u16*)((char*)d_ws + xb_bytes);
    float* P  = (float*)((char*)d_ws + xb_bytes + wb_bytes);

    cvt_x_kernel<<<(N_BATCH * D_IN / 8) / 256, 256, 0, stream>>>(x, xb);
    prep_w_kernel<<<(E_OUT * D_IN) / 256, 256, 0, stream>>>(w, wb);

    gemm_split_kernel<<<128 * 4 * NSPLIT, 256, 0, stream>>>(xb, wb, P);

    reduce_norm_kernel<<<N_BATCH / 4, 256, 0, stream>>>(P, b, out);
}

// Round 4
// 280.143 us; speedup vs baseline: 1.0680x; 1.0145x over previous
//
#include <hip/hip_runtime.h>
#include <hip/hip_bf16.h>
#include <stdint.h>

#define N_BATCH 16384
#define D_IN    2048
#define E_OUT   512
#define K_CONV  1537   // D_IN - E_OUT + 1
#define EPS_N   1e-12f
#define BKD     64     // K-depth per barrier
#define N_ITERS 26     // 1664 / BKD (band-limited K range, uniform for all blocks)

typedef unsigned short u16;
typedef __bf16 bf16x8 __attribute__((ext_vector_type(8)));
typedef float  f32x4  __attribute__((ext_vector_type(4)));

__device__ __forceinline__ unsigned f2bf(float f) {
    union { float f; unsigned int u; } a; a.f = f;
    unsigned int r = a.u + 0x7FFFu + ((a.u >> 16) & 1u);   // RNE
    return r >> 16;
}

// ---------------- densify banded W into bf16 (E_OUT x D_IN) ----------------
__global__ __launch_bounds__(256) void prep_w_kernel(const float* __restrict__ w,
                                                     u16* __restrict__ wb) {
    int idx = blockIdx.x * 256 + threadIdx.x;
    int e = idx >> 11;
    int d = idx & (D_IN - 1);
    int k = d - e;
    float v = (k >= 0 && k < K_CONV) ? w[e * K_CONV + k] : 0.0f;
    wb[idx] = (u16)f2bf(v);
}

// ---------------- fused cvt + bf16 MFMA GEMM + bias + row-ssq ----------------
// A: x fp32 (N_BATCH x D_IN) — converted to bf16 during LDS staging (saves the
// standalone 201 MB cvt pass). B: densified w bf16. C: pre-norm out (bias added).
// Psq[n_idx*N_BATCH + row]: this block's 128-col contribution to row sum-of-squares.
// Grid 512 = 128 m-tiles x 4 n-tiles, 2 blocks/CU, whole grid co-resident.
__global__ __launch_bounds__(256, 2) void gemm_fused_kernel(const float* __restrict__ A,
                                                            const u16* __restrict__ B,
                                                            const float* __restrict__ bias,
                                                            float* __restrict__ C,
                                                            float* __restrict__ Psq) {
    __shared__ __align__(16) u16 As[8][128][8];   // 16 KB, k-plane layout
    __shared__ __align__(16) u16 Bs[8][128][8];   // 16 KB
    __shared__ float ssq_lds[128];

    const int tid  = threadIdx.x;
    const int lane = tid & 63;
    const int wave = tid >> 6;
    const int quad = lane >> 4;
    const int r16  = lane & 15;
    const int wm   = (wave >> 1) << 6;
    const int wn   = (wave & 1) << 6;

    // XCD-aware decode: 4 n-tiles of one m-row adjacent on one XCD (L%8 = xcd)
    const int L     = blockIdx.x;        // [0, 512)
    const int xcd   = L & 7;
    const int s     = L >> 3;            // [0, 64)
    const int n_idx = s & 3;
    const int m_idx = (s >> 2) * 8 + xcd;

    const int m0 = m_idx * 128;
    const int n0 = n_idx * 128;
    const int k_begin = n0;              // band-limited K: [n0, n0+1664)

    // staging map: 1024 16B-chunks per matrix per iter, 4 per thread
    const float* ag[4];
    const u16*   bg[4];
    u16* as_[4];
    u16* bs_[4];
#pragma unroll
    for (int c = 0; c < 4; ++c) {
        const int li  = tid + 256 * c;
        const int row = li & 127;
        const int kc  = li >> 7;         // [0, 8) octet index
        ag[c] = A + (size_t)(m0 + row) * D_IN + k_begin + kc * 8;
        bg[c] = B + (size_t)(n0 + row) * D_IN + k_begin + kc * 8;
        as_[c] = &As[0][0][0] + li * 8;
        bs_[c] = &Bs[0][0][0] + li * 8;
    }

    f32x4 acc[4][4] = {};

    for (int it = 0; it < N_ITERS; ++it) {
        // B: async global->LDS (bf16 already)
#pragma unroll
        for (int c = 0; c < 4; ++c)
            __builtin_amdgcn_global_load_lds((const __attribute__((address_space(1))) void*)bg[c],
                                             (__attribute__((address_space(3))) void*)bs_[c], 16, 0, 0);
        // A: fp32 loads -> RNE pack to bf16 -> ds_write_b128
        f32x4 ar[4][2];
#pragma unroll
        for (int c = 0; c < 4; ++c) {
            ar[c][0] = *(const f32x4*)(ag[c]);
            ar[c][1] = *(const f32x4*)(ag[c] + 4);
        }
#pragma unroll
        for (int c = 0; c < 4; ++c) {
            uint4 o;
            o.x = f2bf(ar[c][0][0]) | (f2bf(ar[c][0][1]) << 16);
            o.y = f2bf(ar[c][0][2]) | (f2bf(ar[c][0][3]) << 16);
            o.z = f2bf(ar[c][1][0]) | (f2bf(ar[c][1][1]) << 16);
            o.w = f2bf(ar[c][1][2]) | (f2bf(ar[c][1][3]) << 16);
            *(uint4*)as_[c] = o;
        }
#pragma unroll
        for (int c = 0; c < 4; ++c) { ag[c] += BKD; bg[c] += BKD; }

        __syncthreads();

#pragma unroll
        for (int kk = 0; kk < 2; ++kk) {
            bf16x8 af[4], bf[4];
#pragma unroll
            for (int t4 = 0; t4 < 4; ++t4)
                af[t4] = *(const bf16x8*)&As[kk * 4 + quad][wm + t4 * 16 + r16][0];
#pragma unroll
            for (int t4 = 0; t4 < 4; ++t4)
                bf[t4] = *(const bf16x8*)&Bs[kk * 4 + quad][wn + t4 * 16 + r16][0];
#pragma unroll
            for (int i = 0; i < 4; ++i)
#pragma unroll
                for (int j = 0; j < 4; ++j)
                    acc[i][j] = __builtin_amdgcn_mfma_f32_16x16x32_bf16(af[i], bf[j], acc[i][j], 0, 0, 0);
        }

        __syncthreads();
    }

    // ---- epilogue: bias add, store pre-norm C, per-row sum-of-squares ----
    if (tid < 128) ssq_lds[tid] = 0.0f;

    float ssq_t[16];
#pragma unroll
    for (int t = 0; t < 16; ++t) ssq_t[t] = 0.0f;

#pragma unroll
    for (int j = 0; j < 4; ++j) {
        const int col = n0 + wn + j * 16 + r16;
        const float bv = bias[col];
#pragma unroll
        for (int i = 0; i < 4; ++i) {
            const int rowb = m0 + wm + i * 16 + quad * 4;
#pragma unroll
            for (int rg = 0; rg < 4; ++rg) {
                const float v = acc[i][j][rg] + bv;
                C[(size_t)(rowb + rg) * E_OUT + col] = v;
                ssq_t[i * 4 + rg] += v * v;
            }
        }
    }

    // reduce over the 16 lanes (r16) sharing each row within this wave
#pragma unroll
    for (int off = 1; off <= 8; off <<= 1)
#pragma unroll
        for (int t = 0; t < 16; ++t)
            ssq_t[t] += __shfl_xor(ssq_t[t], off, 64);

    __syncthreads();   // ssq_lds zero-init visible
    if (r16 == 0) {
#pragma unroll
        for (int i = 0; i < 4; ++i)
#pragma unroll
            for (int rg = 0; rg < 4; ++rg)
                atomicAdd(&ssq_lds[wm + i * 16 + quad * 4 + rg], ssq_t[i * 4 + rg]);
    }
    __syncthreads();
    if (tid < 128)
        Psq[(size_t)n_idx * N_BATCH + m0 + tid] = ssq_lds[tid];
}

// ---------------- lite norm: out *= 1/max(sqrt(sum Psq), eps) ----------------
__global__ __launch_bounds__(256) void norm_kernel(float* __restrict__ out,
                                                   const float* __restrict__ Psq) {
    const int wave = threadIdx.x >> 6;
    const int lane = threadIdx.x & 63;
    const size_t row = (size_t)blockIdx.x * 4 + wave;
    const float ss = Psq[row] + Psq[N_BATCH + row] +
                     Psq[2 * N_BATCH + row] + Psq[3 * N_BATCH + row];
    const float inv = 1.0f / fmaxf(sqrtf(ss), EPS_N);
    float4* p = (float4*)(out + row * E_OUT);
    float4 v0 = p[lane * 2];
    float4 v1 = p[lane * 2 + 1];
    v0.x *= inv; v0.y *= inv; v0.z *= inv; v0.w *= inv;
    v1.x *= inv; v1.y *= inv; v1.z *= inv; v1.w *= inv;
    p[lane * 2] = v0;
    p[lane * 2 + 1] = v1;
}

// ---------------- fallback: fused naive fp32 (only if ws too small) ----------------
__global__ __launch_bounds__(256) void naive_kernel(const float* __restrict__ x,
                                                    const float* __restrict__ w,
                                                    const float* __restrict__ b,
                                                    float* __restrict__ out) {
    __shared__ float xs[D_IN];
    __shared__ float os[E_OUT];
    __shared__ float red[4];
    const int n = blockIdx.x;
    const float* xr = x + (size_t)n * D_IN;
    for (int i = threadIdx.x; i < D_IN; i += 256) xs[i] = xr[i];
    __syncthreads();
    for (int i = threadIdx.x; i < E_OUT; i += 256) {
        float s = b[i];
        const float* wr = w + (size_t)i * K_CONV;
        for (int k = 0; k < K_CONV; ++k) s += wr[k] * xs[i + k];
        os[i] = s;
    }
    __syncthreads();
    float ss = 0.0f;
    for (int i = threadIdx.x; i < E_OUT; i += 256) ss += os[i] * os[i];
#pragma unroll
    for (int off = 32; off > 0; off >>= 1) ss += __shfl_xor(ss, off, 64);
    if ((threadIdx.x & 63) == 0) red[threadIdx.x >> 6] = ss;
    __syncthreads();
    const float inv = 1.0f / fmaxf(sqrtf(red[0] + red[1] + red[2] + red[3]), EPS_N);
    float* orow = out + (size_t)n * E_OUT;
    for (int i = threadIdx.x; i < E_OUT; i += 256) orow[i] = os[i] * inv;
}

extern "C" void kernel_launch(void* const* d_in, const int* in_sizes, int n_in,
                              void* d_out, int out_size, void* d_ws, size_t ws_size,
                              hipStream_t stream) {
    const float* x = (const float*)d_in[0];
    const float* w = (const float*)d_in[1];
    const float* b = (const float*)d_in[2];
    float* out = (float*)d_out;

    const size_t wb_bytes  = (size_t)E_OUT * D_IN * sizeof(u16);   // 2 MiB
    const size_t psq_bytes = (size_t)4 * N_BATCH * sizeof(float);  // 256 KiB

    if (ws_size < wb_bytes + psq_bytes) {
        naive_kernel<<<N_BATCH, 256, 0, stream>>>(x, w, b, out);
        return;
    }

    u16*   wb  = (u16*)d_ws;
    float* Psq = (float*)((char*)d_ws + wb_bytes);

    prep_w_kernel<<<(E_OUT * D_IN) / 256, 256, 0, stream>>>(w, wb);

    gemm_fused_kernel<<<512, 256, 0, stream>>>(x, wb, b, out, Psq);

    norm_kernel<<<N_BATCH / 4, 256, 0, stream>>>(out, Psq);
}

// Round 5
// 275.603 us; speedup vs baseline: 1.0856x; 1.0165x over previous
//
#include <hip/hip_runtime.h>
#include <hip/hip_bf16.h>
#include <stdint.h>

#define N_BATCH 16384
#define D_IN    2048
#define E_OUT   512
#define K_CONV  1537   // D_IN - E_OUT + 1
#define EPS_N   1e-12f
#define BKD     64     // K-depth per iteration
#define N_ITERS 26     // 1664 / BKD (band-limited K range, uniform for all blocks)

typedef unsigned short u16;
typedef __bf16 bf16x8 __attribute__((ext_vector_type(8)));
typedef float  f32x4  __attribute__((ext_vector_type(4)));

__device__ __forceinline__ unsigned f2bf_sw(float f) {
    union { float f; unsigned int u; } a; a.f = f;
    unsigned int r = a.u + 0x7FFFu + ((a.u >> 16) & 1u);   // RNE
    return r >> 16;
}

__device__ __forceinline__ unsigned pk_bf16(float a, float b) {
#if __has_builtin(__builtin_amdgcn_cvt_pk_bf16_f32)
    typedef __bf16 bf16x2 __attribute__((ext_vector_type(2)));
    bf16x2 r = __builtin_amdgcn_cvt_pk_bf16_f32(a, b);     // HW RNE, 1 inst / 2 elems
    union { bf16x2 v; unsigned u; } c; c.v = r;
    return c.u;
#else
    return f2bf_sw(a) | (f2bf_sw(b) << 16);
#endif
}

// ---------------- densify banded W into bf16 (E_OUT x D_IN) ----------------
__global__ __launch_bounds__(256) void prep_w_kernel(const float* __restrict__ w,
                                                     u16* __restrict__ wb) {
    int idx = blockIdx.x * 256 + threadIdx.x;
    int e = idx >> 11;
    int d = idx & (D_IN - 1);
    int k = d - e;
    float v = (k >= 0 && k < K_CONV) ? w[e * K_CONV + k] : 0.0f;
    wb[idx] = (u16)f2bf_sw(v);
}

// ---------------- fused cvt + bf16 MFMA GEMM + bias + row-ssq ----------------
// Software-pipelined: double-buffered LDS, ONE barrier/iter; A fp32->bf16 pack
// reads registers prefetched TWO iterations earlier (completed by the previous
// barrier's vmcnt(0) drain -> zero-stall pack). B staged via global_load_lds.
__global__ __launch_bounds__(256, 2) void gemm_fused_kernel(const float* __restrict__ A,
                                                            const u16* __restrict__ B,
                                                            const float* __restrict__ bias,
                                                            float* __restrict__ C,
                                                            float* __restrict__ Psq) {
    __shared__ __align__(16) u16 As[2][8][128][8];   // 2 x 16 KB, k-plane layout
    __shared__ __align__(16) u16 Bs[2][8][128][8];   // 2 x 16 KB
    __shared__ float ssq_lds[128];

    const int tid  = threadIdx.x;
    const int lane = tid & 63;
    const int wave = tid >> 6;
    const int quad = lane >> 4;
    const int r16  = lane & 15;
    const int wm   = (wave >> 1) << 6;
    const int wn   = (wave & 1) << 6;

    // XCD-aware decode: 4 n-tiles of one m-row adjacent on one XCD (L%8 = xcd)
    const int L     = blockIdx.x;        // [0, 512)
    const int xcd   = L & 7;
    const int s     = L >> 3;            // [0, 64)
    const int n_idx = s & 3;
    const int m_idx = (s >> 2) * 8 + xcd;

    const int m0 = m_idx * 128;
    const int n0 = n_idx * 128;
    const int k_begin = n0;              // band-limited K: [n0, n0+1664)

    // staging map: 1024 16B-chunks per matrix per tile, 4 per thread
    const float* agN[4];                 // next A tile to PREFETCH (reg loads)
    const u16*   bgN[4];                 // next B tile to stage (glds)
    u16* asP[2][4];
    u16* bsP[2][4];
#pragma unroll
    for (int c = 0; c < 4; ++c) {
        const int li  = tid + 256 * c;
        const int row = li & 127;
        const int kc  = li >> 7;         // [0, 8) octet index
        agN[c] = A + (size_t)(m0 + row) * D_IN + k_begin + kc * 8;
        bgN[c] = B + (size_t)(n0 + row) * D_IN + k_begin + kc * 8;
        asP[0][c] = &As[0][0][0][0] + li * 8;
        asP[1][c] = &As[1][0][0][0] + li * 8;
        bsP[0][c] = &Bs[0][0][0][0] + li * 8;
        bsP[1][c] = &Bs[1][0][0][0] + li * 8;
    }

    f32x4 acc[4][4] = {};
    f32x4 arE[8], arO[8];                // A reg slots: tile parity even / odd

#define LOAD_A(dst, off)                                        \
    _Pragma("unroll")                                           \
    for (int c = 0; c < 4; ++c) {                               \
        dst[2*c]   = *(const f32x4*)(agN[c] + (off));           \
        dst[2*c+1] = *(const f32x4*)(agN[c] + (off) + 4);       \
    }

#define PACK_A(src, buf)                                        \
    _Pragma("unroll")                                           \
    for (int c = 0; c < 4; ++c) {                               \
        uint4 o;                                                \
        o.x = pk_bf16(src[2*c][0],   src[2*c][1]);              \
        o.y = pk_bf16(src[2*c][2],   src[2*c][3]);              \
        o.z = pk_bf16(src[2*c+1][0], src[2*c+1][1]);            \
        o.w = pk_bf16(src[2*c+1][2], src[2*c+1][3]);            \
        *(uint4*)asP[buf][c] = o;                               \
    }

#define GLDS_B(buf)                                             \
    _Pragma("unroll")                                           \
    for (int c = 0; c < 4; ++c)                                 \
        __builtin_amdgcn_global_load_lds(                       \
            (const __attribute__((address_space(1))) void*)bgN[c], \
            (__attribute__((address_space(3))) void*)bsP[buf][c], 16, 0, 0);

#define COMPUTE(buf)                                            \
    _Pragma("unroll")                                           \
    for (int kk = 0; kk < 2; ++kk) {                            \
        bf16x8 af[4], bf[4];                                    \
        _Pragma("unroll")                                       \
        for (int t4 = 0; t4 < 4; ++t4)                          \
            af[t4] = *(const bf16x8*)&As[buf][kk*4+quad][wm + t4*16 + r16][0]; \
        _Pragma("unroll")                                       \
        for (int t4 = 0; t4 < 4; ++t4)                          \
            bf[t4] = *(const bf16x8*)&Bs[buf][kk*4+quad][wn + t4*16 + r16][0]; \
        _Pragma("unroll")                                       \
        for (int i = 0; i < 4; ++i)                             \
            _Pragma("unroll")                                   \
            for (int j = 0; j < 4; ++j)                         \
                acc[i][j] = __builtin_amdgcn_mfma_f32_16x16x32_bf16(af[i], bf[j], acc[i][j], 0, 0, 0); \
    }

    // ---- prologue: tile0 sync-staged to buf0; tile1 regs prefetched ----
    {
        f32x4 arT[8];
        LOAD_A(arT, 0);                  // tile 0
        LOAD_A(arO, BKD);                // tile 1 (odd slot) — in flight
        GLDS_B(0);                       // B tile 0 -> buf0
#pragma unroll
        for (int c = 0; c < 4; ++c) bgN[c] += BKD;     // -> tile 1
#pragma unroll
        for (int c = 0; c < 4; ++c) agN[c] += 2 * BKD; // -> tile 2
        PACK_A(arT, 0);                  // waits only on arT
        __syncthreads();                 // drains glds(0) + arO loads + ds_writes
    }

    // ---- main loop: 13 double-iterations, one barrier per iteration ----
    for (int p = 0; p < 13; ++p) {
        // even iter: it = 2p; compute buf0, stage tile it+1 -> buf1
        {
            const int it = 2 * p;
            if (it + 1 < N_ITERS) {
                GLDS_B(1);
#pragma unroll
                for (int c = 0; c < 4; ++c) bgN[c] += BKD;
                if (it + 2 < N_ITERS) {
                    LOAD_A(arE, 0);      // tile it+2 (even slot)
#pragma unroll
                    for (int c = 0; c < 4; ++c) agN[c] += BKD;
                }
                PACK_A(arO, 1);          // tile it+1 — regs complete (prev barrier)
            }
            COMPUTE(0);
            __syncthreads();
        }
        // odd iter: it = 2p+1; compute buf1, stage tile it+1 -> buf0
        {
            const int it = 2 * p + 1;
            if (it + 1 < N_ITERS) {
                GLDS_B(0);
#pragma unroll
                for (int c = 0; c < 4; ++c) bgN[c] += BKD;
                if (it + 2 < N_ITERS) {
                    LOAD_A(arO, 0);      // tile it+2 (odd slot)
#pragma unroll
                    for (int c = 0; c < 4; ++c) agN[c] += BKD;
                }
                PACK_A(arE, 0);          // tile it+1
            }
            COMPUTE(1);
            __syncthreads();
        }
    }

    // ---- epilogue: bias add, store pre-norm C, per-row sum-of-squares ----
    if (tid < 128) ssq_lds[tid] = 0.0f;

    float ssq_t[16];
#pragma unroll
    for (int t = 0; t < 16; ++t) ssq_t[t] = 0.0f;

#pragma unroll
    for (int j = 0; j < 4; ++j) {
        const int col = n0 + wn + j * 16 + r16;
        const float bv = bias[col];
#pragma unroll
        for (int i = 0; i < 4; ++i) {
            const int rowb = m0 + wm + i * 16 + quad * 4;
#pragma unroll
            for (int rg = 0; rg < 4; ++rg) {
                const float v = acc[i][j][rg] + bv;
                C[(size_t)(rowb + rg) * E_OUT + col] = v;
                ssq_t[i * 4 + rg] += v * v;
            }
        }
    }

#pragma unroll
    for (int off = 1; off <= 8; off <<= 1)
#pragma unroll
        for (int t = 0; t < 16; ++t)
            ssq_t[t] += __shfl_xor(ssq_t[t], off, 64);

    __syncthreads();
    if (r16 == 0) {
#pragma unroll
        for (int i = 0; i < 4; ++i)
#pragma unroll
            for (int rg = 0; rg < 4; ++rg)
                atomicAdd(&ssq_lds[wm + i * 16 + quad * 4 + rg], ssq_t[i * 4 + rg]);
    }
    __syncthreads();
    if (tid < 128)
        Psq[(size_t)n_idx * N_BATCH + m0 + tid] = ssq_lds[tid];
}

// ---------------- lite norm: out *= 1/max(sqrt(sum Psq), eps) ----------------
__global__ __launch_bounds__(256) void norm_kernel(float* __restrict__ out,
                                                   const float* __restrict__ Psq) {
    const int wave = threadIdx.x >> 6;
    const int lane = threadIdx.x & 63;
    const size_t row = (size_t)blockIdx.x * 4 + wave;
    const float ss = Psq[row] + Psq[N_BATCH + row] +
                     Psq[2 * N_BATCH + row] + Psq[3 * N_BATCH + row];
    const float inv = 1.0f / fmaxf(sqrtf(ss), EPS_N);
    float4* p = (float4*)(out + row * E_OUT);
    float4 v0 = p[lane * 2];
    float4 v1 = p[lane * 2 + 1];
    v0.x *= inv; v0.y *= inv; v0.z *= inv; v0.w *= inv;
    v1.x *= inv; v1.y *= inv; v1.z *= inv; v1.w *= inv;
    p[lane * 2] = v0;
    p[lane * 2 + 1] = v1;
}

// ---------------- fallback: fused naive fp32 (only if ws too small) ----------------
__global__ __launch_bounds__(256) void naive_kernel(const float* __restrict__ x,
                                                    const float* __restrict__ w,
                                                    const float* __restrict__ b,
                                                    float* __restrict__ out) {
    __shared__ float xs[D_IN];
    __shared__ float os[E_OUT];
    __shared__ float red[4];
    const int n = blockIdx.x;
    const float* xr = x + (size_t)n * D_IN;
    for (int i = threadIdx.x; i < D_IN; i += 256) xs[i] = xr[i];
    __syncthreads();
    for (int i = threadIdx.x; i < E_OUT; i += 256) {
        float s = b[i];
        const float* wr = w + (size_t)i * K_CONV;
        for (int k = 0; k < K_CONV; ++k) s += wr[k] * xs[i + k];
        os[i] = s;
    }
    __syncthreads();
    float ss = 0.0f;
    for (int i = threadIdx.x; i < E_OUT; i += 256) ss += os[i] * os[i];
#pragma unroll
    for (int off = 32; off > 0; off >>= 1) ss += __shfl_xor(ss, off, 64);
    if ((threadIdx.x & 63) == 0) red[threadIdx.x >> 6] = ss;
    __syncthreads();
    const float inv = 1.0f / fmaxf(sqrtf(red[0] + red[1] + red[2] + red[3]), EPS_N);
    float* orow = out + (size_t)n * E_OUT;
    for (int i = threadIdx.x; i < E_OUT; i += 256) orow[i] = os[i] * inv;
}

extern "C" void kernel_launch(void* const* d_in, const int* in_sizes, int n_in,
                              void* d_out, int out_size, void* d_ws, size_t ws_size,
                              hipStream_t stream) {
    const float* x = (const float*)d_in[0];
    const float* w = (const float*)d_in[1];
    const float* b = (const float*)d_in[2];
    float* out = (float*)d_out;

    const size_t wb_bytes  = (size_t)E_OUT * D_IN * sizeof(u16);   // 2 MiB
    const size_t psq_bytes = (size_t)4 * N_BATCH * sizeof(float);  // 256 KiB

    if (ws_size < wb_bytes + psq_bytes) {
        naive_kernel<<<N_BATCH, 256, 0, stream>>>(x, w, b, out);
        return;
    }

    u16*   wb  = (u16*)d_ws;
    float* Psq = (float*)((char*)d_ws + wb_bytes);

    prep_w_kernel<<<(E_OUT * D_IN) / 256, 256, 0, stream>>>(w, wb);

    gemm_fused_kernel<<<512, 256, 0, stream>>>(x, wb, b, out, Psq);

    norm_kernel<<<N_BATCH / 4, 256, 0, stream>>>(out, Psq);
}